// Round 1
// 304.867 us; speedup vs baseline: 1.0078x; 1.0078x over previous
//
#include <hip/hip_runtime.h>

typedef __attribute__((ext_vector_type(8))) short short8;     // 8 x bf16 (4 VGPRs) MFMA frag
typedef __attribute__((ext_vector_type(4))) float floatx4;    // MFMA accumulator
typedef unsigned short u16;
typedef unsigned int   u32;

__device__ __forceinline__ u32 f2bf(float f) {               // fp32 -> bf16, round-to-nearest-even
  u32 u = __float_as_uint(f);
  return (u + 0x7fffu + ((u >> 16) & 1u)) >> 16;
}

__device__ __forceinline__ short8 cvt8v(float4 a, float4 b) { // 8 fp32 -> bf16x8 fragment
  short8 r;
  r[0] = (short)f2bf(a.x); r[1] = (short)f2bf(a.y); r[2] = (short)f2bf(a.z); r[3] = (short)f2bf(a.w);
  r[4] = (short)f2bf(b.x); r[5] = (short)f2bf(b.y); r[6] = (short)f2bf(b.z); r[7] = (short)f2bf(b.w);
  return r;
}

// ---------------------------------------------------------------------------
// Fully fused kernel. Grid = 1024 blocks (b: 4 x s-tile: 256), 256 threads.
// Phase 0: wave 0 computes Q (64x64 Householder product, fp32) into LDS as
//          bf16 Q and Q^T (stride 72 u16 -> 2-way-bank-free b128 frag reads).
// Phase 1: each of the 4 waves handles 8 (tensor,head) combos for the SAME
//          16 tokens; cos/sin staged once per block in LDS (stride 68);
//          x tile depth-1 prefetched.
// LDS map (36352 B total -> 4 blocks/CU):
//   [    0,  9216) Qb  u16[64][72]
//   [ 9216, 18432) Qt  u16[64][72]
//   [18432, 22784) cos f32[16][68]   (phase0 alias: sv f32[32][64] = 8 KB)
//   [22784, 27136) sin f32[16][68]
//   [27136, 36352) sh  u16[4][1152]  (per-wave bf16 round-trip, stride 72)
// ---------------------------------------------------------------------------
#define QB_OFF  0
#define QT_OFF  9216
#define COS_OFF 18432
#define SIN_OFF 22784
#define SH_OFF  27136
#define SV_OFF  18432

__global__ void __launch_bounds__(256, 4) rnrope_fused(
    const float* __restrict__ qp, const float* __restrict__ kp,
    const float* __restrict__ cosp, const float* __restrict__ sinp,
    const float* __restrict__ vsp, float* __restrict__ outp) {
  __shared__ __align__(16) char smem[36352];
  u16*   qb = (u16*)(smem + QB_OFF);
  u16*   qt = (u16*)(smem + QT_OFF);
  float* cs = (float*)(smem + COS_OFF);
  float* sn = (float*)(smem + SIN_OFF);
  float* sv = (float*)(smem + SV_OFF);

  const int tid  = threadIdx.x;
  const int lane = tid & 63;
  const int t    = lane & 15;    // token within tile
  const int quad = lane >> 4;
  const int wave = tid >> 6;
  u16* shw = (u16*)(smem + SH_OFF) + wave * 1152;

  const int b  = blockIdx.x >> 8;     // 0..3
  const int st = blockIdx.x & 255;    // 0..255
  const int s  = st << 4;

  // --- stage vs (2048 f32) into LDS; cos/sin (1 float4 each per thread) to regs ---
  *(float4*)(sv + tid * 8)     = *(const float4*)(vsp + tid * 8);
  *(float4*)(sv + tid * 8 + 4) = *(const float4*)(vsp + tid * 8 + 4);
  const int tk  = tid >> 4;           // 0..15 token
  const int off = (tid & 15) << 2;    // 0..60 feature
  const float4 creg = *(const float4*)(cosp + (((b << 12) + s + tk) << 6) + off);
  const float4 sreg = *(const float4*)(sinp + (((b << 12) + s + tk) << 6) + off);
  __syncthreads();                    // sv ready

  // --- Phase 0: wave 0 builds Q sequentially (identical math to old hh_kernel) ---
  if (wave == 0) {
    const int j = lane;
    float col[64];
#pragma unroll
    for (int i = 0; i < 64; i++) col[i] = (i == j) ? 1.f : 0.f;
#pragma unroll 1
    for (int r = 0; r < 32; r++) {
      const float* vr = sv + r * 64;
      float vv0 = 0, vv1 = 0, vv2 = 0, vv3 = 0, w0 = 0, w1 = 0, w2 = 0, w3 = 0;
#pragma unroll
      for (int i = 0; i < 64; i += 4) {
        float4 v4 = *(const float4*)(vr + i);
        vv0 += v4.x * v4.x; vv1 += v4.y * v4.y; vv2 += v4.z * v4.z; vv3 += v4.w * v4.w;
        w0 += v4.x * col[i]; w1 += v4.y * col[i + 1]; w2 += v4.z * col[i + 2]; w3 += v4.w * col[i + 3];
      }
      float coef = 2.f / (((vv0 + vv1) + (vv2 + vv3)) + 1e-8f);
      float cw = coef * ((w0 + w1) + (w2 + w3));
#pragma unroll
      for (int i = 0; i < 64; i += 4) {
        float4 v4 = *(const float4*)(vr + i);
        col[i]     -= v4.x * cw;
        col[i + 1] -= v4.y * cw;
        col[i + 2] -= v4.z * cw;
        col[i + 3] -= v4.w * cw;
      }
    }
#pragma unroll
    for (int i = 0; i < 64; i += 2) {           // Qb[i][j]=Q[i][j]; Qt[j][i]=Q[i][j]
      u16 v0 = (u16)f2bf(col[i]);
      u16 v1 = (u16)f2bf(col[i + 1]);
      qb[(i) * 72 + j]     = v0;
      qb[(i + 1) * 72 + j] = v1;
      *(u32*)&qt[j * 72 + i] = (u32)v0 | ((u32)v1 << 16);
    }
  }
  __syncthreads();                    // Q ready, sv dead
  *(float4*)(cs + tk * 68 + off) = creg;
  *(float4*)(sn + tk * 68 + off) = sreg;
  __syncthreads();                    // cos/sin ready

  // --- Phase 1: 8 (tensor,head) combos per wave, same 16 tokens ---
  const int hbase = b << 4;
  auto xptr = [&](int c) -> const float* {
    const float* base = (c < 16) ? qp : kp;
    return base + ((((hbase + (c & 15)) << 12) + s + t) << 6);
  };

  const int c0 = wave << 3;
  float4 n0, n1, n2, n3;
  {
    const float* p = xptr(c0);
    n0 = *(const float4*)(p + quad * 8);
    n1 = *(const float4*)(p + quad * 8 + 4);
    n2 = *(const float4*)(p + 32 + quad * 8);
    n3 = *(const float4*)(p + 32 + quad * 8 + 4);
  }

#pragma unroll 1
  for (int it = 0; it < 8; ++it) {
    const int c = c0 + it;
    float4 x0 = n0, x1 = n1, x2 = n2, x3 = n3;
    if (it < 7) {                     // depth-1 prefetch of next combo's x tile
      const float* p = xptr(c + 1);
      n0 = *(const float4*)(p + quad * 8);
      n1 = *(const float4*)(p + quad * 8 + 4);
      n2 = *(const float4*)(p + 32 + quad * 8);
      n3 = *(const float4*)(p + 32 + quad * 8 + 4);
    }
    short8 bq0 = cvt8v(x0, x1);       // B[k=quad*8+j][n=t], k 0..31
    short8 bq1 = cvt8v(x2, x3);       // k 32..63

    int qoff = 0;                     // defeat LICM: keep Q-frag reads inside the loop
    asm volatile("" : "+v"(qoff));

    // GEMM1: qi[t][i], i = i0*16 + quad*4 + r ; A-frags from LDS Qb
    floatx4 acc[4];
#pragma unroll
    for (int i0 = 0; i0 < 4; i0++) {
      short8 a0 = *(const short8*)(qb + qoff + (i0 * 16 + t) * 72 + quad * 8);
      short8 a1 = *(const short8*)(qb + qoff + (i0 * 16 + t) * 72 + 32 + quad * 8);
      floatx4 z = {0.f, 0.f, 0.f, 0.f};
      z = __builtin_amdgcn_mfma_f32_16x16x32_bf16(a0, bq0, z, 0, 0, 0);
      z = __builtin_amdgcn_mfma_f32_16x16x32_bf16(a1, bq1, z, 0, 0, 0);
      acc[i0] = z;
    }

    // RoPE (lane-local; partner feature i±32 is tile i0^2, same reg) + pack to LDS
    float4 c4[4], s4[4];
#pragma unroll
    for (int i0 = 0; i0 < 4; i0++) {
      c4[i0] = *(const float4*)(cs + t * 68 + i0 * 16 + quad * 4);
      s4[i0] = *(const float4*)(sn + t * 68 + i0 * 16 + quad * 4);
    }
#pragma unroll
    for (int i0 = 0; i0 < 4; i0++) {
      const int p = i0 ^ 2;
      const float sg = (i0 < 2) ? -1.f : 1.f;
      float r0 = acc[i0][0] * c4[i0].x + sg * acc[p][0] * s4[i0].x;
      float r1 = acc[i0][1] * c4[i0].y + sg * acc[p][1] * s4[i0].y;
      float r2 = acc[i0][2] * c4[i0].z + sg * acc[p][2] * s4[i0].z;
      float r3 = acc[i0][3] * c4[i0].w + sg * acc[p][3] * s4[i0].w;
      u32 lo = f2bf(r0) | (f2bf(r1) << 16);
      u32 hi = f2bf(r2) | (f2bf(r3) << 16);
      *(uint2*)&shw[t * 72 + i0 * 16 + quad * 4] = make_uint2(lo, hi);
    }

    __builtin_amdgcn_wave_barrier();  // wave-synchronous LDS: DS pipe in-order per wave
    short8 br0 = *(const short8*)&shw[t * 72 + quad * 8];
    short8 br1 = *(const short8*)&shw[t * 72 + 32 + quad * 8];

    // GEMM2 + store: out[t][o], o = o0*16 + quad*4 + r ; A-frags from LDS Qt
    float* op = outp + ((c < 16) ? 0 : 16777216) + ((((hbase + (c & 15)) << 12) + s + t) << 6);
#pragma unroll
    for (int o0 = 0; o0 < 4; o0++) {
      short8 a0 = *(const short8*)(qt + qoff + (o0 * 16 + t) * 72 + quad * 8);
      short8 a1 = *(const short8*)(qt + qoff + (o0 * 16 + t) * 72 + 32 + quad * 8);
      floatx4 z = {0.f, 0.f, 0.f, 0.f};
      z = __builtin_amdgcn_mfma_f32_16x16x32_bf16(a0, br0, z, 0, 0, 0);
      z = __builtin_amdgcn_mfma_f32_16x16x32_bf16(a1, br1, z, 0, 0, 0);
      *(float4*)(op + o0 * 16 + quad * 4) = make_float4(z[0], z[1], z[2], z[3]);
    }
    __builtin_amdgcn_wave_barrier();
  }
}

extern "C" void kernel_launch(void* const* d_in, const int* in_sizes, int n_in,
                              void* d_out, int out_size, void* d_ws, size_t ws_size,
                              hipStream_t stream) {
  const float* q    = (const float*)d_in[0];
  const float* k    = (const float*)d_in[1];
  const float* cosp = (const float*)d_in[2];
  const float* sinp = (const float*)d_in[3];
  const float* vs   = (const float*)d_in[4];
  float* out = (float*)d_out;
  hipLaunchKernelGGL(rnrope_fused, dim3(1024), dim3(256), 0, stream,
                     q, k, cosp, sinp, vs, out);
}

// Round 2
// 262.369 us; speedup vs baseline: 1.1710x; 1.1620x over previous
//
#include <hip/hip_runtime.h>

typedef __attribute__((ext_vector_type(8))) short short8;     // 8 x bf16 (4 VGPRs) MFMA frag
typedef __attribute__((ext_vector_type(4))) float floatx4;    // MFMA accumulator
typedef unsigned short u16;
typedef unsigned int   u32;

__device__ __forceinline__ u32 f2bf(float f) {               // fp32 -> bf16, round-to-nearest-even
  u32 u = __float_as_uint(f);
  return (u + 0x7fffu + ((u >> 16) & 1u)) >> 16;
}

__device__ __forceinline__ short8 cvt8v(float4 a, float4 b) { // 8 fp32 -> bf16x8 fragment
  short8 r;
  r[0] = (short)f2bf(a.x); r[1] = (short)f2bf(a.y); r[2] = (short)f2bf(a.z); r[3] = (short)f2bf(a.w);
  r[4] = (short)f2bf(b.x); r[5] = (short)f2bf(b.y); r[6] = (short)f2bf(b.z); r[7] = (short)f2bf(b.w);
  return r;
}

// ---------------------------------------------------------------------------
// Fused kernel, grid = 1024 blocks (b:4 x s-tile:256), 256 threads.
// Phase 0 (cooperative, NO per-thread col[64] -> no scratch spill):
//   thread (j=tid&63, seg=tid>>6) owns Q[seg*16..seg*16+15][j] in col16[16].
//   Per Householder round: 16-elem partial dot w_seg,j -> LDS reduce (double-
//   buffered, 1 syncthreads/round), coef broadcast, 16-elem update.
// Phase 1: 4 waves x 8 (tensor,head) combos for the same 16 tokens.
//   cos/sin live in 32 per-lane VGPRs (loaded once). x tile depth-1 prefetch.
// LDS map (29728 B -> 5 blocks/CU possible):
//   [    0,  9216) Qb u16[64][72]
//   [ 9216, 18432) Qt u16[64][72]
//   [18432, 27648) sh u16[4][1152]   (phase0 alias: sv f32[32][64] = 8 KB)
//   [27648, 29696) pw f32[2][4][64]  (partial dot reduce, double-buffered)
//   [29696, 29728) pv f32[2][4]      (partial ||v||^2)
// ---------------------------------------------------------------------------
#define QB_OFF  0
#define QT_OFF  9216
#define SH_OFF  18432
#define SV_OFF  18432
#define PW_OFF  27648
#define PV_OFF  29696

__global__ void __launch_bounds__(256, 5) rnrope_fused(
    const float* __restrict__ qp, const float* __restrict__ kp,
    const float* __restrict__ cosp, const float* __restrict__ sinp,
    const float* __restrict__ vsp, float* __restrict__ outp) {
  __shared__ __align__(16) char smem[29728];
  u16*   qb = (u16*)(smem + QB_OFF);
  u16*   qt = (u16*)(smem + QT_OFF);
  float* sv = (float*)(smem + SV_OFF);
  float* pw = (float*)(smem + PW_OFF);
  float* pv = (float*)(smem + PV_OFF);

  const int tid  = threadIdx.x;
  const int lane = tid & 63;
  const int t    = lane & 15;    // token within tile
  const int quad = lane >> 4;
  const int wave = tid >> 6;
  u16* shw = (u16*)(smem + SH_OFF) + wave * 1152;

  const int b = blockIdx.x >> 8;          // 0..3
  const int s = (blockIdx.x & 255) << 4;  // token tile start

  // --- stage vs (2048 f32) into LDS ---
  *(float4*)(sv + tid * 8)     = *(const float4*)(vsp + tid * 8);
  *(float4*)(sv + tid * 8 + 4) = *(const float4*)(vsp + tid * 8 + 4);
  __syncthreads();

  // --- Phase 0: cooperative Householder, 16 rows of one column per thread ---
  const int j   = lane;
  const int seg = wave;
  float col16[16];
#pragma unroll
  for (int i = 0; i < 16; i++) col16[i] = (seg * 16 + i == j) ? 1.f : 0.f;

#pragma unroll 1
  for (int r = 0; r < 32; r++) {
    const float* vr = sv + r * 64 + seg * 16;
    float4 va = *(const float4*)(vr);
    float4 vb = *(const float4*)(vr + 4);
    float4 vc = *(const float4*)(vr + 8);
    float4 vd = *(const float4*)(vr + 12);
    float w = va.x * col16[0]  + va.y * col16[1]  + va.z * col16[2]  + va.w * col16[3]
            + vb.x * col16[4]  + vb.y * col16[5]  + vb.z * col16[6]  + vb.w * col16[7]
            + vc.x * col16[8]  + vc.y * col16[9]  + vc.z * col16[10] + vc.w * col16[11]
            + vd.x * col16[12] + vd.y * col16[13] + vd.z * col16[14] + vd.w * col16[15];
    float vvp = va.x * va.x + va.y * va.y + va.z * va.z + va.w * va.w
              + vb.x * vb.x + vb.y * vb.y + vb.z * vb.z + vb.w * vb.w
              + vc.x * vc.x + vc.y * vc.y + vc.z * vc.z + vc.w * vc.w
              + vd.x * vd.x + vd.y * vd.y + vd.z * vd.z + vd.w * vd.w;
    const int par = (r & 1);
    pw[par * 256 + seg * 64 + j] = w;
    if (j == 0) pv[par * 4 + seg] = vvp;
    __syncthreads();
    const float* pwr = pw + par * 256;
    const float* pvr = pv + par * 4;
    float wsum = (pwr[j] + pwr[64 + j]) + (pwr[128 + j] + pwr[192 + j]);
    float vv   = (pvr[0] + pvr[1]) + (pvr[2] + pvr[3]);
    float cw = (2.f / (vv + 1e-8f)) * wsum;
    col16[0]  -= va.x * cw; col16[1]  -= va.y * cw; col16[2]  -= va.z * cw; col16[3]  -= va.w * cw;
    col16[4]  -= vb.x * cw; col16[5]  -= vb.y * cw; col16[6]  -= vb.z * cw; col16[7]  -= vb.w * cw;
    col16[8]  -= vc.x * cw; col16[9]  -= vc.y * cw; col16[10] -= vc.z * cw; col16[11] -= vc.w * cw;
    col16[12] -= vd.x * cw; col16[13] -= vd.y * cw; col16[14] -= vd.z * cw; col16[15] -= vd.w * cw;
  }

  // --- write Q (bf16) into LDS in both layouts ---
#pragma unroll
  for (int i = 0; i < 16; i++) qb[(seg * 16 + i) * 72 + j] = (u16)f2bf(col16[i]);
  {
    u32 pk[8];
#pragma unroll
    for (int i = 0; i < 8; i++) pk[i] = f2bf(col16[2 * i]) | (f2bf(col16[2 * i + 1]) << 16);
    u16* qtr = qt + j * 72 + seg * 16;           // byte offset 144*j+32*seg, 8-aligned
    *(uint2*)(qtr)      = make_uint2(pk[0], pk[1]);
    *(uint2*)(qtr + 4)  = make_uint2(pk[2], pk[3]);
    *(uint2*)(qtr + 8)  = make_uint2(pk[4], pk[5]);
    *(uint2*)(qtr + 12) = make_uint2(pk[6], pk[7]);
  }
  __syncthreads();                    // Q ready; sv region now reusable as sh

  // --- Phase 1 setup: cos/sin into registers (tokens fixed per wave) ---
  const float* crow = cosp + (((b << 12) + s + t) << 6);
  const float* srow = sinp + (((b << 12) + s + t) << 6);
  float4 c4[4], s4[4];
#pragma unroll
  for (int i0 = 0; i0 < 4; i0++) {
    c4[i0] = *(const float4*)(crow + i0 * 16 + quad * 4);
    s4[i0] = *(const float4*)(srow + i0 * 16 + quad * 4);
  }

  const int hbase = b << 4;
  auto xptr = [&](int c) -> const float* {
    const float* base = (c < 16) ? qp : kp;
    return base + ((((hbase + (c & 15)) << 12) + s + t) << 6);
  };

  const int c0 = wave << 3;
  float4 n0, n1, n2, n3;
  {
    const float* p = xptr(c0);
    n0 = *(const float4*)(p + quad * 8);
    n1 = *(const float4*)(p + quad * 8 + 4);
    n2 = *(const float4*)(p + 32 + quad * 8);
    n3 = *(const float4*)(p + 32 + quad * 8 + 4);
  }

#pragma unroll 1
  for (int it = 0; it < 8; ++it) {
    const int c = c0 + it;
    float4 x0 = n0, x1 = n1, x2 = n2, x3 = n3;
    if (it < 7) {                     // depth-1 prefetch of next combo's x tile
      const float* p = xptr(c + 1);
      n0 = *(const float4*)(p + quad * 8);
      n1 = *(const float4*)(p + quad * 8 + 4);
      n2 = *(const float4*)(p + 32 + quad * 8);
      n3 = *(const float4*)(p + 32 + quad * 8 + 4);
    }
    short8 bq0 = cvt8v(x0, x1);       // B[k=quad*8+j][n=t], k 0..31
    short8 bq1 = cvt8v(x2, x3);       // k 32..63

    int qoff = 0;                     // defeat LICM: keep Q-frag reads inside the loop
    asm volatile("" : "+v"(qoff));

    // GEMM1: qi[t][i], i = i0*16 + quad*4 + r ; A-frags from LDS Qb
    floatx4 acc[4];
#pragma unroll
    for (int i0 = 0; i0 < 4; i0++) {
      short8 a0 = *(const short8*)(qb + qoff + (i0 * 16 + t) * 72 + quad * 8);
      short8 a1 = *(const short8*)(qb + qoff + (i0 * 16 + t) * 72 + 32 + quad * 8);
      floatx4 z = {0.f, 0.f, 0.f, 0.f};
      z = __builtin_amdgcn_mfma_f32_16x16x32_bf16(a0, bq0, z, 0, 0, 0);
      z = __builtin_amdgcn_mfma_f32_16x16x32_bf16(a1, bq1, z, 0, 0, 0);
      acc[i0] = z;
    }

    // RoPE (lane-local; partner feature i±32 is tile i0^2, same reg) + pack to LDS
#pragma unroll
    for (int i0 = 0; i0 < 4; i0++) {
      const int p = i0 ^ 2;
      const float sg = (i0 < 2) ? -1.f : 1.f;
      float r0 = acc[i0][0] * c4[i0].x + sg * acc[p][0] * s4[i0].x;
      float r1 = acc[i0][1] * c4[i0].y + sg * acc[p][1] * s4[i0].y;
      float r2 = acc[i0][2] * c4[i0].z + sg * acc[p][2] * s4[i0].z;
      float r3 = acc[i0][3] * c4[i0].w + sg * acc[p][3] * s4[i0].w;
      u32 lo = f2bf(r0) | (f2bf(r1) << 16);
      u32 hi = f2bf(r2) | (f2bf(r3) << 16);
      *(uint2*)&shw[t * 72 + i0 * 16 + quad * 4] = make_uint2(lo, hi);
    }

    __builtin_amdgcn_wave_barrier();  // wave-synchronous LDS: DS pipe in-order per wave
    short8 br0 = *(const short8*)&shw[t * 72 + quad * 8];
    short8 br1 = *(const short8*)&shw[t * 72 + 32 + quad * 8];

    // GEMM2 + store: out[t][o], o = o0*16 + quad*4 + r ; A-frags from LDS Qt
    float* op = outp + ((c < 16) ? 0 : 16777216) + ((((hbase + (c & 15)) << 12) + s + t) << 6);
#pragma unroll
    for (int o0 = 0; o0 < 4; o0++) {
      short8 a0 = *(const short8*)(qt + qoff + (o0 * 16 + t) * 72 + quad * 8);
      short8 a1 = *(const short8*)(qt + qoff + (o0 * 16 + t) * 72 + 32 + quad * 8);
      floatx4 z = {0.f, 0.f, 0.f, 0.f};
      z = __builtin_amdgcn_mfma_f32_16x16x32_bf16(a0, br0, z, 0, 0, 0);
      z = __builtin_amdgcn_mfma_f32_16x16x32_bf16(a1, br1, z, 0, 0, 0);
      *(float4*)(op + o0 * 16 + quad * 4) = make_float4(z[0], z[1], z[2], z[3]);
    }
    __builtin_amdgcn_wave_barrier();
  }
}

extern "C" void kernel_launch(void* const* d_in, const int* in_sizes, int n_in,
                              void* d_out, int out_size, void* d_ws, size_t ws_size,
                              hipStream_t stream) {
  const float* q    = (const float*)d_in[0];
  const float* k    = (const float*)d_in[1];
  const float* cosp = (const float*)d_in[2];
  const float* sinp = (const float*)d_in[3];
  const float* vs   = (const float*)d_in[4];
  float* out = (float*)d_out;
  hipLaunchKernelGGL(rnrope_fused, dim3(1024), dim3(256), 0, stream,
                     q, k, cosp, sinp, vs, out);
}